// Round 1
// baseline (1950.594 us; speedup 1.0000x reference)
//
#include <hip/hip_runtime.h>
#include <math.h>

namespace {
constexpr int B_ = 2, C_ = 48, H_ = 64, W_ = 64;
constexpr int N_ = H_ * W_;    // 4096 tokens (global)
constexpr int NP_ = 1024;      // 32*32 tokens (patch)
constexpr int C4_ = 4 * C_;    // 192
constexpr float EPS_ = 1e-5f;
}

// ---------------- global projections: proj[X][b][d][n] = sum_c W_X[d,c] x_X[b,c,n]
__global__ __launch_bounds__(256) void k_proj_global(
    const float* __restrict__ x0, const float* __restrict__ x1,
    const float* __restrict__ x2, const float* __restrict__ x3,
    const float* __restrict__ w0, const float* __restrict__ w1,
    const float* __restrict__ w2, const float* __restrict__ w3,
    float* __restrict__ proj) {
  int idx = blockIdx.x * 256 + threadIdx.x;
  int n = idx & (N_ - 1);
  int rest = idx >> 12;
  int d = rest % C_; rest /= C_;
  int b = rest % B_;
  int X = rest / B_;
  const float* xp = (X == 0) ? x0 : (X == 1) ? x1 : (X == 2) ? x2 : x3;
  const float* wp = (X == 0) ? w0 : (X == 1) ? w1 : (X == 2) ? w2 : w3;
  const float* xr = xp + (size_t)b * C_ * N_ + n;
  const float* wr = wp + d * C_;
  float acc = 0.f;
#pragma unroll
  for (int c = 0; c < C_; ++c) acc = fmaf(wr[c], xr[(size_t)c * N_], acc);
  proj[idx] = acc;
}

// ---------------- patch projections: proj[X][b][p][d][t], t = 32x32 crop token
__global__ __launch_bounds__(256) void k_proj_patch(
    const float* __restrict__ x0, const float* __restrict__ x1,
    const float* __restrict__ x2, const float* __restrict__ x3,
    const float* __restrict__ w0, const float* __restrict__ w1,
    const float* __restrict__ w2, const float* __restrict__ w3,
    float* __restrict__ proj) {
  int idx = blockIdx.x * 256 + threadIdx.x;  // (((X*B+b)*9+p)*C+d)*NP + t
  int t = idx & (NP_ - 1);
  int rest = idx >> 10;
  int d = rest % C_; rest /= C_;
  int p = rest % 9;  rest /= 9;
  int b = rest % B_;
  int X = rest / B_;
  const float* xp = (X == 0) ? x0 : (X == 1) ? x1 : (X == 2) ? x2 : x3;
  const float* wp = (X == 0) ? w0 : (X == 1) ? w1 : (X == 2) ? w2 : w3;
  int r0 = (p / 3) * 16, c0 = (p % 3) * 16;
  int rr = r0 + (t >> 5), cc = c0 + (t & 31);
  const float* xr = xp + ((size_t)(b * C_) * H_ + rr) * W_ + cc;
  const float* wr = wp + (size_t)(p * C_ + d) * C_;
  float acc = 0.f;
#pragma unroll
  for (int c = 0; c < C_; ++c) acc = fmaf(wr[c], xr[(size_t)c * H_ * W_], acc);
  proj[idx] = acc;
}

// ---------------- energy GEMM: e[z][n][m] = sum_c q[z][c][n] * k[z][c][m]
__global__ __launch_bounds__(256) void k_energy(
    const float* __restrict__ q, const float* __restrict__ k,
    float* __restrict__ e, int nt) {
  __shared__ __align__(16) float As[C_][64];
  __shared__ __align__(16) float Bs[C_][64];
  int tid = threadIdx.x;
  int mt = blockIdx.x * 64, ntile = blockIdx.y * 64;
  size_t zoff = (size_t)blockIdx.z * C_ * nt;
  const float* qm = q + zoff;
  const float* km = k + zoff;
  float* em = e + (size_t)blockIdx.z * nt * nt;
  for (int i = tid; i < C_ * 64; i += 256) {
    int c = i >> 6, j = i & 63;
    As[c][j] = qm[(size_t)c * nt + ntile + j];
    Bs[c][j] = km[(size_t)c * nt + mt + j];
  }
  __syncthreads();
  int tn = (tid & 15) * 4, tm = (tid >> 4) * 4;
  float acc[4][4] = {};
#pragma unroll
  for (int c = 0; c < C_; ++c) {
    float4 av = *(const float4*)&As[c][tn];
    float4 bv = *(const float4*)&Bs[c][tm];
    acc[0][0] = fmaf(av.x, bv.x, acc[0][0]); acc[0][1] = fmaf(av.x, bv.y, acc[0][1]);
    acc[0][2] = fmaf(av.x, bv.z, acc[0][2]); acc[0][3] = fmaf(av.x, bv.w, acc[0][3]);
    acc[1][0] = fmaf(av.y, bv.x, acc[1][0]); acc[1][1] = fmaf(av.y, bv.y, acc[1][1]);
    acc[1][2] = fmaf(av.y, bv.z, acc[1][2]); acc[1][3] = fmaf(av.y, bv.w, acc[1][3]);
    acc[2][0] = fmaf(av.z, bv.x, acc[2][0]); acc[2][1] = fmaf(av.z, bv.y, acc[2][1]);
    acc[2][2] = fmaf(av.z, bv.z, acc[2][2]); acc[2][3] = fmaf(av.z, bv.w, acc[2][3]);
    acc[3][0] = fmaf(av.w, bv.x, acc[3][0]); acc[3][1] = fmaf(av.w, bv.y, acc[3][1]);
    acc[3][2] = fmaf(av.w, bv.z, acc[3][2]); acc[3][3] = fmaf(av.w, bv.w, acc[3][3]);
  }
#pragma unroll
  for (int i = 0; i < 4; ++i) {
    float4 o = make_float4(acc[i][0], acc[i][1], acc[i][2], acc[i][3]);
    *(float4*)&em[(size_t)(ntile + tn + i) * nt + mt + tm] = o;
  }
}

// ---------------- row stats: stats[z][n] = {rowmin, 1/sum_m exp(rowmin - e)}
template <int PER>
__global__ __launch_bounds__(256) void k_stats(
    const float* __restrict__ e, float* __restrict__ stats, int nt) {
  int n = blockIdx.x;
  const float* row = e + ((size_t)blockIdx.y * nt + n) * nt;
  int tid = threadIdx.x;
  float vals[PER];
  float mn = 3.0e38f;
#pragma unroll
  for (int i = 0; i < PER; ++i) {
    float v = row[tid + 256 * i];
    vals[i] = v;
    mn = fminf(mn, v);
  }
#pragma unroll
  for (int off = 32; off > 0; off >>= 1) mn = fminf(mn, __shfl_down(mn, off));
  __shared__ float sred[4];
  if ((tid & 63) == 0) sred[tid >> 6] = mn;
  __syncthreads();
  mn = fminf(fminf(sred[0], sred[1]), fminf(sred[2], sred[3]));
  __syncthreads();
  float se = 0.f;
#pragma unroll
  for (int i = 0; i < PER; ++i) se += __expf(mn - vals[i]);
#pragma unroll
  for (int off = 32; off > 0; off >>= 1) se += __shfl_down(se, off);
  if ((tid & 63) == 0) sred[tid >> 6] = se;
  __syncthreads();
  if (tid == 0) {
    float Z = sred[0] + sred[1] + sred[2] + sred[3];
    float* st = stats + ((size_t)blockIdx.y * nt + n) * 2;
    st[0] = mn;
    st[1] = 1.0f / Z;
  }
}

// ---------------- PV: out[z][c][m] += sum_n v[z][c][n] * exp(rowmin_n - e[n][m]) * Zinv_n
template <int NT, int NSPLIT>
__global__ __launch_bounds__(256) void k_pv(
    const float* __restrict__ v, const float* __restrict__ e,
    const float* __restrict__ stats, float* __restrict__ out, size_t out_zstride) {
  __shared__ __align__(16) float Vs[64][52];  // [n][c], padded stride
  __shared__ __align__(16) float Ws[64][64];  // [n][m]
  int tid = threadIdx.x;
  int mt = blockIdx.x * 64;
  int z = blockIdx.z;
  const float* vz = v + (size_t)z * C_ * NT;
  const float* ez = e + (size_t)z * NT * NT;
  const float* st = stats + (size_t)z * NT * 2;
  float* oz = out + (size_t)z * out_zstride;
  constexpr int CH = NT / NSPLIT;
  int n0beg = blockIdx.y * CH;
  float acc[12] = {};
  int m = tid & 63, cg = tid >> 6, cbase = cg * 12;
  for (int n0 = n0beg; n0 < n0beg + CH; n0 += 64) {
    for (int i = tid; i < C_ * 64; i += 256) {
      int c = i >> 6, j = i & 63;
      Vs[j][c] = vz[(size_t)c * NT + n0 + j];
    }
    for (int i = tid; i < 64 * 64; i += 256) {
      int r = i >> 6, j = i & 63;
      int n = n0 + r;
      Ws[r][j] = __expf(st[2 * n] - ez[(size_t)n * NT + mt + j]) * st[2 * n + 1];
    }
    __syncthreads();
#pragma unroll 16
    for (int nn = 0; nn < 64; ++nn) {
      float w = Ws[nn][m];
      const float4 v0 = *(const float4*)&Vs[nn][cbase];
      const float4 v1 = *(const float4*)&Vs[nn][cbase + 4];
      const float4 v2 = *(const float4*)&Vs[nn][cbase + 8];
      acc[0] = fmaf(v0.x, w, acc[0]);  acc[1] = fmaf(v0.y, w, acc[1]);
      acc[2] = fmaf(v0.z, w, acc[2]);  acc[3] = fmaf(v0.w, w, acc[3]);
      acc[4] = fmaf(v1.x, w, acc[4]);  acc[5] = fmaf(v1.y, w, acc[5]);
      acc[6] = fmaf(v1.z, w, acc[6]);  acc[7] = fmaf(v1.w, w, acc[7]);
      acc[8] = fmaf(v2.x, w, acc[8]);  acc[9] = fmaf(v2.y, w, acc[9]);
      acc[10] = fmaf(v2.z, w, acc[10]); acc[11] = fmaf(v2.w, w, acc[11]);
    }
    __syncthreads();
  }
#pragma unroll
  for (int i = 0; i < 12; ++i)
    atomicAdd(&oz[(size_t)(cbase + i) * NT + mt + m], acc[i]);
}

// ---------------- global fuse + BN + relu; combined = input + gamma_all * relu(...)
__global__ __launch_bounds__(256) void k_fuse_global(
    const float* __restrict__ cat, const float* __restrict__ fw,
    const float* __restrict__ fb, const float* __restrict__ fg,
    const float* __restrict__ fbb, const float* __restrict__ fm,
    const float* __restrict__ fv, const float* __restrict__ gamma_all,
    const float* __restrict__ input, float* __restrict__ comb) {
  int idx = blockIdx.x * 256 + threadIdx.x;  // (b*C+o)*N + n
  int n = idx & (N_ - 1);
  int rest = idx >> 12;
  int o = rest % C_;
  int b = rest / C_;
  const float* cr = cat + (size_t)b * C4_ * N_ + n;
  const float* wr = fw + (size_t)o * C4_;
  float acc = 0.f;
#pragma unroll 8
  for (int c = 0; c < C4_; ++c) acc = fmaf(wr[c], cr[(size_t)c * N_], acc);
  float scale = fg[o] * rsqrtf(fv[o] + EPS_);
  float y = (acc + fb[o] - fm[o]) * scale + fbb[o];
  y = fmaxf(y, 0.f);
  comb[idx] = input[idx] + gamma_all[0] * y;
}

// ---------------- patch fuse + BN + relu + 0.5*gamma_p scale -> py[p][b][o][t]
__global__ __launch_bounds__(256) void k_fuse_patch(
    const float* __restrict__ pcat, const float* __restrict__ fw,
    const float* __restrict__ fb, const float* __restrict__ fg,
    const float* __restrict__ fbb, const float* __restrict__ fm,
    const float* __restrict__ fv, const float* __restrict__ gamma_p,
    float* __restrict__ py) {
  int idx = blockIdx.x * 256 + threadIdx.x;  // ((p*B+b)*C+o)*NP + t
  int t = idx & (NP_ - 1);
  int rest = idx >> 10;
  int o = rest % C_; rest /= C_;
  int b = rest % B_;
  int p = rest / B_;
  const float* cr = pcat + ((size_t)(p * B_ + b) * C4_) * NP_ + t;
  const float* wr = fw + (size_t)(p * C_ + o) * C4_;
  float acc = 0.f;
#pragma unroll 8
  for (int c = 0; c < C4_; ++c) acc = fmaf(wr[c], cr[(size_t)c * NP_], acc);
  int po = p * C_ + o;
  float scale = fg[po] * rsqrtf(fv[po] + EPS_);
  float y = (acc + fb[po] - fm[po]) * scale + fbb[po];
  y = fmaxf(y, 0.f);
  py[idx] = 0.5f * gamma_p[p] * y;
}

// ---------------- overlap-accumulate patches into combined (in place)
__global__ __launch_bounds__(256) void k_combine(
    const float* __restrict__ py, float* __restrict__ comb) {
  int idx = blockIdx.x * 256 + threadIdx.x;  // (b*C+ch)*N + h*W + w
  int w = idx & (W_ - 1);
  int h = (idx >> 6) & (H_ - 1);
  int rest = idx >> 12;
  int ch = rest % C_;
  int b = rest / C_;
  float val = comb[idx];
#pragma unroll
  for (int p = 0; p < 9; ++p) {
    int r0 = (p / 3) * 16, c0 = (p % 3) * 16;
    if (h >= r0 && h < r0 + 32 && w >= c0 && w < c0 + 32)
      val += py[((size_t)(p * B_ + b) * C_ + ch) * NP_ + (h - r0) * 32 + (w - c0)];
  }
  comb[idx] = val;
}

// ---------------- 3x3 conv (SAME) + BN + relu -> out
__global__ __launch_bounds__(256) void k_conv(
    const float* __restrict__ comb, const float* __restrict__ cw,
    const float* __restrict__ cb, const float* __restrict__ cg,
    const float* __restrict__ cbb, const float* __restrict__ cm,
    const float* __restrict__ cv, float* __restrict__ out) {
  int idx = blockIdx.x * 256 + threadIdx.x;
  int w = idx & (W_ - 1);
  int h = (idx >> 6) & (H_ - 1);
  int rest = idx >> 12;
  int o = rest % C_;
  int b = rest / C_;
  float acc = 0.f;
  for (int c = 0; c < C_; ++c) {
    const float* src = comb + ((size_t)(b * C_ + c) * H_) * W_;
    const float* wr = cw + ((size_t)(o * C_ + c)) * 9;
#pragma unroll
    for (int kh = 0; kh < 3; ++kh) {
      int hh = h + kh - 1;
      if (hh < 0 || hh >= H_) continue;
#pragma unroll
      for (int kw = 0; kw < 3; ++kw) {
        int ww = w + kw - 1;
        if (ww < 0 || ww >= W_) continue;
        acc = fmaf(src[hh * W_ + ww], wr[kh * 3 + kw], acc);
      }
    }
  }
  float scale = cg[o] * rsqrtf(cv[o] + EPS_);
  float y = (acc + cb[o] - cm[o]) * scale + cbb[o];
  out[idx] = fmaxf(y, 0.f);
}

extern "C" void kernel_launch(void* const* d_in, const int* in_sizes, int n_in,
                              void* d_out, int out_size, void* d_ws, size_t ws_size,
                              hipStream_t stream) {
  (void)in_sizes; (void)n_in; (void)out_size; (void)ws_size;
  const float* x[4];
  const float* Wall[4];
  const float* Wp[4];
  for (int i = 0; i < 4; ++i) {
    x[i]    = (const float*)d_in[i];
    Wall[i] = (const float*)d_in[4 + i];
    Wp[i]   = (const float*)d_in[8 + i];
  }
  const float* fuse_w  = (const float*)d_in[12];
  const float* fuse_b  = (const float*)d_in[13];
  const float* fuse_g  = (const float*)d_in[14];
  const float* fuse_bb = (const float*)d_in[15];
  const float* fuse_m  = (const float*)d_in[16];
  const float* fuse_v  = (const float*)d_in[17];
  const float* fuseP_w  = (const float*)d_in[18];
  const float* fuseP_b  = (const float*)d_in[19];
  const float* fuseP_g  = (const float*)d_in[20];
  const float* fuseP_bb = (const float*)d_in[21];
  const float* fuseP_m  = (const float*)d_in[22];
  const float* fuseP_v  = (const float*)d_in[23];
  const float* gamma_all = (const float*)d_in[24];
  const float* gamma_p   = (const float*)d_in[25];
  const float* out_w  = (const float*)d_in[26];
  const float* out_b  = (const float*)d_in[27];
  const float* out_g  = (const float*)d_in[28];
  const float* out_bb = (const float*)d_in[29];
  const float* out_m  = (const float*)d_in[30];
  const float* out_v  = (const float*)d_in[31];

  float* ws = (float*)d_ws;
  size_t off = 0;
  float* projg = ws + off; off += (size_t)4 * B_ * C_ * N_;        // 1,572,864
  float* cat   = ws + off; off += (size_t)B_ * C4_ * N_;           // 1,572,864
  float* stats = ws + off; off += (size_t)9 * NP_ * 2;             // 18,432 (covers N_*2 too)
  float* comb  = ws + off; off += (size_t)B_ * C_ * N_;            // 393,216
  float* projp = ws + off; off += (size_t)4 * B_ * 9 * C_ * NP_;   // 3,538,944
  float* pcat  = ws + off; off += (size_t)9 * B_ * C4_ * NP_;      // 3,538,944
  float* py    = ws + off; off += (size_t)9 * B_ * C_ * NP_;       // 884,736
  float* ebuf  = ws + off; off += (size_t)N_ * N_;                 // 16,777,216 (>= 9*NP*NP)

  dim3 blk(256);

  // ---- global branch
  k_proj_global<<<(4 * B_ * C_ * N_) / 256, blk, 0, stream>>>(
      x[0], x[1], x[2], x[3], Wall[0], Wall[1], Wall[2], Wall[3], projg);
  hipMemsetAsync(cat, 0, (size_t)B_ * C4_ * N_ * sizeof(float), stream);
  for (int X = 0; X < 4; ++X)
    for (int b = 0; b < B_; ++b) {
      const float* q = projg + (size_t)(0 * B_ + b) * C_ * N_;
      const float* k = projg + (size_t)(X * B_ + b) * C_ * N_;
      k_energy<<<dim3(N_ / 64, N_ / 64, 1), blk, 0, stream>>>(q, k, ebuf, N_);
      k_stats<16><<<dim3(N_, 1), blk, 0, stream>>>(ebuf, stats, N_);
      k_pv<N_, 8><<<dim3(N_ / 64, 8, 1), blk, 0, stream>>>(
          k, ebuf, stats, cat + ((size_t)b * C4_ + X * C_) * N_, 0);
    }
  k_fuse_global<<<(B_ * C_ * N_) / 256, blk, 0, stream>>>(
      cat, fuse_w, fuse_b, fuse_g, fuse_bb, fuse_m, fuse_v, gamma_all, x[0], comb);

  // ---- patch branch
  k_proj_patch<<<(4 * B_ * 9 * C_ * NP_) / 256, blk, 0, stream>>>(
      x[0], x[1], x[2], x[3], Wp[0], Wp[1], Wp[2], Wp[3], projp);
  hipMemsetAsync(pcat, 0, (size_t)9 * B_ * C4_ * NP_ * sizeof(float), stream);
  for (int X = 0; X < 4; ++X)
    for (int b = 0; b < B_; ++b) {
      const float* q = projp + (size_t)(0 * B_ + b) * 9 * C_ * NP_;
      const float* k = projp + (size_t)(X * B_ + b) * 9 * C_ * NP_;
      k_energy<<<dim3(NP_ / 64, NP_ / 64, 9), blk, 0, stream>>>(q, k, ebuf, NP_);
      k_stats<4><<<dim3(NP_, 9), blk, 0, stream>>>(ebuf, stats, NP_);
      k_pv<NP_, 4><<<dim3(NP_ / 64, 4, 9), blk, 0, stream>>>(
          k, ebuf, stats, pcat + ((size_t)b * C4_ + X * C_) * NP_,
          (size_t)B_ * C4_ * NP_);
    }
  k_fuse_patch<<<(9 * B_ * C_ * NP_) / 256, blk, 0, stream>>>(
      pcat, fuseP_w, fuseP_b, fuseP_g, fuseP_bb, fuseP_m, fuseP_v, gamma_p, py);

  // ---- combine + conv
  k_combine<<<(B_ * C_ * N_) / 256, blk, 0, stream>>>(py, comb);
  k_conv<<<(B_ * C_ * N_) / 256, blk, 0, stream>>>(
      comb, out_w, out_b, out_g, out_bb, out_m, out_v, (float*)d_out);
}

// Round 2
// 692.222 us; speedup vs baseline: 2.8179x; 2.8179x over previous
//
#include <hip/hip_runtime.h>
#include <math.h>

typedef _Float16 f16;
typedef f16 f16x8 __attribute__((ext_vector_type(8)));
typedef float f32x4 __attribute__((ext_vector_type(4)));

namespace {
constexpr int B_ = 2, C_ = 48, H_ = 64, W_ = 64;
constexpr int N_ = H_ * W_;    // 4096
constexpr int NP_ = 1024;      // 32*32
constexpr int C4_ = 4 * C_;    // 192
constexpr float EPS_ = 1e-5f;
}

#define MFMA(a, b, c) __builtin_amdgcn_mfma_f32_16x16x32_f16((a), (b), (c), 0, 0, 0)

// ---------------- global projections -> fp16 dual layout
// pn[z2][48][4096] (z2 = X*2+b), pt[z2][4096][64] zero-padded c>=48
__global__ __launch_bounds__(256) void k_proj_g(
    const float* __restrict__ x0, const float* __restrict__ x1,
    const float* __restrict__ x2, const float* __restrict__ x3,
    const float* __restrict__ w0, const float* __restrict__ w1,
    const float* __restrict__ w2, const float* __restrict__ w3,
    f16* __restrict__ pn, f16* __restrict__ pt) {
  __shared__ float Ws[48 * 48];
  int tid = threadIdx.x;
  int b = blockIdx.y, X = blockIdx.z;
  const float* xp = X == 0 ? x0 : X == 1 ? x1 : X == 2 ? x2 : x3;
  const float* wp = X == 0 ? w0 : X == 1 ? w1 : X == 2 ? w2 : w3;
  for (int i = tid; i < 2304; i += 256) Ws[i] = wp[i];
  __syncthreads();
  int n = blockIdx.x * 256 + tid;
  const float* xb = xp + (size_t)b * 48 * 4096 + n;
  float acc[48];
#pragma unroll
  for (int d = 0; d < 48; ++d) acc[d] = 0.f;
  for (int c0 = 0; c0 < 48; c0 += 4) {
    float xv0 = xb[(size_t)(c0 + 0) * 4096];
    float xv1 = xb[(size_t)(c0 + 1) * 4096];
    float xv2 = xb[(size_t)(c0 + 2) * 4096];
    float xv3 = xb[(size_t)(c0 + 3) * 4096];
#pragma unroll
    for (int d = 0; d < 48; ++d) {
      const float4 wv = *(const float4*)&Ws[d * 48 + c0];
      acc[d] = fmaf(wv.x, xv0, fmaf(wv.y, xv1, fmaf(wv.z, xv2, fmaf(wv.w, xv3, acc[d]))));
    }
  }
  int z2 = X * 2 + b;
  f16* pnb = pn + ((size_t)z2 * 48) * 4096 + n;
#pragma unroll
  for (int d = 0; d < 48; ++d) pnb[(size_t)d * 4096] = (f16)acc[d];
  f16* ptb = pt + ((size_t)z2 * 4096 + n) * 64;
#pragma unroll
  for (int s = 0; s < 6; ++s) {
    f16x8 v;
#pragma unroll
    for (int j = 0; j < 8; ++j) v[j] = (f16)acc[s * 8 + j];
    *(f16x8*)(ptb + s * 8) = v;
  }
  f16x8 zv = {0, 0, 0, 0, 0, 0, 0, 0};
  *(f16x8*)(ptb + 48) = zv;
  *(f16x8*)(ptb + 56) = zv;
}

// ---------------- patch projections -> fp16 dual layout
// pn[z9][48][1024] (z9=(X*2+b)*9+p), pt[z9][1024][64]
__global__ __launch_bounds__(256) void k_proj_p(
    const float* __restrict__ x0, const float* __restrict__ x1,
    const float* __restrict__ x2, const float* __restrict__ x3,
    const float* __restrict__ w0, const float* __restrict__ w1,
    const float* __restrict__ w2, const float* __restrict__ w3,
    f16* __restrict__ pn, f16* __restrict__ pt) {
  __shared__ float Ws[48 * 48];
  int tid = threadIdx.x;
  int p = blockIdx.y;
  int X = blockIdx.z >> 1, b = blockIdx.z & 1;
  const float* xp = X == 0 ? x0 : X == 1 ? x1 : X == 2 ? x2 : x3;
  const float* wp = (X == 0 ? w0 : X == 1 ? w1 : X == 2 ? w2 : w3) + (size_t)p * 2304;
  for (int i = tid; i < 2304; i += 256) Ws[i] = wp[i];
  __syncthreads();
  int t = blockIdx.x * 256 + tid;
  int r0 = (p / 3) * 16, c0w = (p % 3) * 16;
  int rr = r0 + (t >> 5), cc = c0w + (t & 31);
  const float* xb = xp + (size_t)b * 48 * 4096 + rr * 64 + cc;
  float acc[48];
#pragma unroll
  for (int d = 0; d < 48; ++d) acc[d] = 0.f;
  for (int c0 = 0; c0 < 48; c0 += 4) {
    float xv0 = xb[(size_t)(c0 + 0) * 4096];
    float xv1 = xb[(size_t)(c0 + 1) * 4096];
    float xv2 = xb[(size_t)(c0 + 2) * 4096];
    float xv3 = xb[(size_t)(c0 + 3) * 4096];
#pragma unroll
    for (int d = 0; d < 48; ++d) {
      const float4 wv = *(const float4*)&Ws[d * 48 + c0];
      acc[d] = fmaf(wv.x, xv0, fmaf(wv.y, xv1, fmaf(wv.z, xv2, fmaf(wv.w, xv3, acc[d]))));
    }
  }
  int z9 = (X * 2 + b) * 9 + p;
  f16* pnb = pn + ((size_t)z9 * 48) * 1024 + t;
#pragma unroll
  for (int d = 0; d < 48; ++d) pnb[(size_t)d * 1024] = (f16)acc[d];
  f16* ptb = pt + ((size_t)z9 * 1024 + t) * 64;
#pragma unroll
  for (int s = 0; s < 6; ++s) {
    f16x8 v;
#pragma unroll
    for (int j = 0; j < 8; ++j) v[j] = (f16)acc[s * 8 + j];
    *(f16x8*)(ptb + s * 8) = v;
  }
  f16x8 zv = {0, 0, 0, 0, 0, 0, 0, 0};
  *(f16x8*)(ptb + 48) = zv;
  *(f16x8*)(ptb + 56) = zv;
}

// ---------------- stats: A_n = min_m e[n,m] - ln(sum_m exp(min - e))
// e recomputed via MFMA; per-lane online stats, cross-lane merge once.
template <bool PATCH>
__global__ __launch_bounds__(256) void k_stats_f(
    const f16* __restrict__ qT_all, const f16* __restrict__ kT_all,
    float* __restrict__ st_all) {
  constexpr int NT = PATCH ? NP_ : N_;
  int tid = threadIdx.x, wave = tid >> 6, lane = tid & 63, g = lane >> 4, lm = lane & 15;
  int z = blockIdx.y;
  const f16* qT;
  const f16* kT;
  float* st;
  if (PATCH) {
    int b = (z / 9) % 2, p = z % 9;
    qT = qT_all + ((size_t)(b * 9 + p)) * NT * 64;
  } else {
    int b = z & 1;
    qT = qT_all + (size_t)b * NT * 64;
  }
  kT = kT_all + (size_t)z * NT * 64;
  st = st_all + (size_t)z * NT;
  int n0 = blockIdx.x * 64 + wave * 16;
  f16x8 aq0 = *(const f16x8*)(qT + (size_t)(n0 + lm) * 64 + g * 8);
  f16x8 aq1 = *(const f16x8*)(qT + (size_t)(n0 + lm) * 64 + 32 + g * 8);
  float mn[4], zs[4];
#pragma unroll
  for (int r = 0; r < 4; ++r) { mn[r] = 3.0e38f; zs[r] = 0.f; }
  f16x8 bc[4][2], bn[4][2];
#define LOADB(dst, m0_)                                                          \
  do {                                                                           \
    _Pragma("unroll") for (int mf = 0; mf < 4; ++mf) {                           \
      dst[mf][0] = *(const f16x8*)(kT + (size_t)((m0_) + 16 * mf + lm) * 64 + g * 8);      \
      dst[mf][1] = *(const f16x8*)(kT + (size_t)((m0_) + 16 * mf + lm) * 64 + 32 + g * 8); \
    }                                                                            \
  } while (0)
  LOADB(bc, 0);
  for (int m0 = 0; m0 < NT; m0 += 64) {
    int m1 = (m0 + 64 < NT) ? m0 + 64 : m0;
    LOADB(bn, m1);
#pragma unroll
    for (int mf = 0; mf < 4; ++mf) {
      f32x4 e = {0.f, 0.f, 0.f, 0.f};
      e = MFMA(aq0, bc[mf][0], e);
      e = MFMA(aq1, bc[mf][1], e);
#pragma unroll
      for (int r = 0; r < 4; ++r) {
        float v = e[r];
        if (v < mn[r]) { zs[r] = zs[r] * __expf(v - mn[r]) + 1.f; mn[r] = v; }
        else zs[r] += __expf(mn[r] - v);
      }
    }
#pragma unroll
    for (int mf = 0; mf < 4; ++mf) { bc[mf][0] = bn[mf][0]; bc[mf][1] = bn[mf][1]; }
  }
#pragma unroll
  for (int mask = 1; mask < 16; mask <<= 1) {
#pragma unroll
    for (int r = 0; r < 4; ++r) {
      float om = __shfl_xor(mn[r], mask, 64);
      float oz = __shfl_xor(zs[r], mask, 64);
      float m2 = fminf(mn[r], om);
      zs[r] = zs[r] * __expf(m2 - mn[r]) + oz * __expf(m2 - om);
      mn[r] = m2;
    }
  }
  if (lm == 0) {
#pragma unroll
    for (int r = 0; r < 4; ++r) st[n0 + 4 * g + r] = mn[r] - logf(zs[r]);
  }
#undef LOADB
}

// ---------------- PV: out[c,m] = sum_n v[c,n] exp(A_n - e[n,m])
// e recomputed bitwise-identically; w packed fp16 via per-wave swizzled LDS bounce.
template <bool PATCH>
__global__ __launch_bounds__(256) void k_pv_f(
    const f16* __restrict__ qT_all, const f16* __restrict__ kT_all,
    const f16* __restrict__ vN_all, const float* __restrict__ st_all,
    float* __restrict__ out_all) {
  constexpr int NT = PATCH ? NP_ : N_;
  constexpr int NTI = NT / 64;
  __shared__ float As[NT];
  __shared__ __align__(16) f16 wt[8192];  // 4 waves x 2 buf x 16m x 64n
  int tid = threadIdx.x, wave = tid >> 6, lane = tid & 63, g = lane >> 4, lm = lane & 15;
  int z = blockIdx.y;
  const f16 *qT, *kT, *vN;
  const float* st;
  float* op;
  if (PATCH) {
    int X = z / 18, b = (z / 9) % 2, p = z % 9;
    qT = qT_all + ((size_t)(b * 9 + p)) * NT * 64;
    op = out_all + ((size_t)((p * 2 + b) * C4_ + X * 48)) * NT;
  } else {
    int X = z >> 1, b = z & 1;
    qT = qT_all + (size_t)b * NT * 64;
    op = out_all + ((size_t)(b * C4_ + X * 48)) * NT;
  }
  kT = kT_all + (size_t)z * NT * 64;
  vN = vN_all + (size_t)z * 48 * NT;
  st = st_all + (size_t)z * NT;
  for (int i = tid; i < NT / 4; i += 256) ((float4*)As)[i] = ((const float4*)st)[i];
  int mw = blockIdx.x * 64 + wave * 16;
  f16x8 bk0 = *(const f16x8*)(kT + (size_t)(mw + lm) * 64 + g * 8);
  f16x8 bk1 = *(const f16x8*)(kT + (size_t)(mw + lm) * 64 + 32 + g * 8);
  __syncthreads();
  f32x4 o0 = {0.f, 0.f, 0.f, 0.f}, o1 = {0.f, 0.f, 0.f, 0.f}, o2 = {0.f, 0.f, 0.f, 0.f};
  f16x8 aqc[4][2], avc[3][2], aqn[4][2], avn[3][2];
#define LOADT(qd, vd, t_)                                                                    \
  do {                                                                                       \
    _Pragma("unroll") for (int nf = 0; nf < 4; ++nf) {                                       \
      qd[nf][0] = *(const f16x8*)(qT + (size_t)((t_) * 64 + 16 * nf + lm) * 64 + g * 8);     \
      qd[nf][1] = *(const f16x8*)(qT + (size_t)((t_) * 64 + 16 * nf + lm) * 64 + 32 + g * 8);\
    }                                                                                        \
    _Pragma("unroll") for (int cf = 0; cf < 3; ++cf) {                                       \
      vd[cf][0] = *(const f16x8*)(vN + (size_t)(16 * cf + lm) * NT + (t_) * 64 + g * 8);     \
      vd[cf][1] = *(const f16x8*)(vN + (size_t)(16 * cf + lm) * NT + (t_) * 64 + 32 + g * 8);\
    }                                                                                        \
  } while (0)
  LOADT(aqc, avc, 0);
  char* wtb = (char*)wt;
  for (int nt = 0; nt < NTI; ++nt) {
    int tn = (nt + 1 < NTI) ? nt + 1 : nt;
    LOADT(aqn, avn, tn);
    f32x4 e[4];
#pragma unroll
    for (int nf = 0; nf < 4; ++nf) {
      f32x4 t = {0.f, 0.f, 0.f, 0.f};
      t = MFMA(aqc[nf][0], bk0, t);
      t = MFMA(aqc[nf][1], bk1, t);
      e[nf] = t;
    }
    char* wbase = wtb + ((size_t)(wave * 2 + (nt & 1)) * 1024) * 2;
#pragma unroll
    for (int nf = 0; nf < 4; ++nf) {
      float4 a4 = *(const float4*)&As[nt * 64 + nf * 16 + g * 4];
      float w0 = __expf(a4.x - e[nf][0]);
      float w1 = __expf(a4.y - e[nf][1]);
      float w2 = __expf(a4.z - e[nf][2]);
      float w3 = __expf(a4.w - e[nf][3]);
      unsigned lo = __builtin_bit_cast(unsigned, __builtin_amdgcn_cvt_pkrtz(w0, w1));
      unsigned hi = __builtin_bit_cast(unsigned, __builtin_amdgcn_cvt_pkrtz(w2, w3));
      int s = 2 * nf + (g >> 1);
      int addr = lm * 128 + ((s ^ (lm & 7)) * 16) + (g & 1) * 8;
      *(uint2*)(wbase + addr) = make_uint2(lo, hi);
    }
    f16x8 bw0 = *(const f16x8*)(wbase + lm * 128 + (((0 + g) ^ (lm & 7)) * 16));
    f16x8 bw1 = *(const f16x8*)(wbase + lm * 128 + (((4 + g) ^ (lm & 7)) * 16));
    o0 = MFMA(avc[0][0], bw0, o0);
    o0 = MFMA(avc[0][1], bw1, o0);
    o1 = MFMA(avc[1][0], bw0, o1);
    o1 = MFMA(avc[1][1], bw1, o1);
    o2 = MFMA(avc[2][0], bw0, o2);
    o2 = MFMA(avc[2][1], bw1, o2);
#pragma unroll
    for (int nf = 0; nf < 4; ++nf) { aqc[nf][0] = aqn[nf][0]; aqc[nf][1] = aqn[nf][1]; }
#pragma unroll
    for (int cf = 0; cf < 3; ++cf) { avc[cf][0] = avn[cf][0]; avc[cf][1] = avn[cf][1]; }
  }
#pragma unroll
  for (int r = 0; r < 4; ++r) {
    op[(size_t)(0 + 4 * g + r) * NT + mw + lm] = o0[r];
    op[(size_t)(16 + 4 * g + r) * NT + mw + lm] = o1[r];
    op[(size_t)(32 + 4 * g + r) * NT + mw + lm] = o2[r];
  }
#undef LOADT
}

// ---------------- global fuse + BN + relu; combined = input + gamma_all * relu(...)
__global__ __launch_bounds__(256) void k_fuse_global(
    const float* __restrict__ cat, const float* __restrict__ fw,
    const float* __restrict__ fb, const float* __restrict__ fg,
    const float* __restrict__ fbb, const float* __restrict__ fm,
    const float* __restrict__ fv, const float* __restrict__ gamma_all,
    const float* __restrict__ input, float* __restrict__ comb) {
  int idx = blockIdx.x * 256 + threadIdx.x;
  int n = idx & (N_ - 1);
  int rest = idx >> 12;
  int o = rest % C_;
  int b = rest / C_;
  const float* cr = cat + (size_t)b * C4_ * N_ + n;
  const float* wr = fw + (size_t)o * C4_;
  float acc = 0.f;
#pragma unroll 8
  for (int c = 0; c < C4_; ++c) acc = fmaf(wr[c], cr[(size_t)c * N_], acc);
  float scale = fg[o] * rsqrtf(fv[o] + EPS_);
  float y = (acc + fb[o] - fm[o]) * scale + fbb[o];
  y = fmaxf(y, 0.f);
  comb[idx] = input[idx] + gamma_all[0] * y;
}

// ---------------- patch fuse + BN + relu + 0.5*gamma_p -> py[p][b][o][t]
__global__ __launch_bounds__(256) void k_fuse_patch(
    const float* __restrict__ pcat, const float* __restrict__ fw,
    const float* __restrict__ fb, const float* __restrict__ fg,
    const float* __restrict__ fbb, const float* __restrict__ fm,
    const float* __restrict__ fv, const float* __restrict__ gamma_p,
    float* __restrict__ py) {
  int idx = blockIdx.x * 256 + threadIdx.x;
  int t = idx & (NP_ - 1);
  int rest = idx >> 10;
  int o = rest % C_; rest /= C_;
  int b = rest % B_;
  int p = rest / B_;
  const float* cr = pcat + ((size_t)(p * B_ + b) * C4_) * NP_ + t;
  const float* wr = fw + (size_t)(p * C_ + o) * C4_;
  float acc = 0.f;
#pragma unroll 8
  for (int c = 0; c < C4_; ++c) acc = fmaf(wr[c], cr[(size_t)c * NP_], acc);
  int po = p * C_ + o;
  float scale = fg[po] * rsqrtf(fv[po] + EPS_);
  float y = (acc + fb[po] - fm[po]) * scale + fbb[po];
  y = fmaxf(y, 0.f);
  py[idx] = 0.5f * gamma_p[p] * y;
}

// ---------------- overlap-accumulate patches into combined (in place)
__global__ __launch_bounds__(256) void k_combine(
    const float* __restrict__ py, float* __restrict__ comb) {
  int idx = blockIdx.x * 256 + threadIdx.x;
  int w = idx & (W_ - 1);
  int h = (idx >> 6) & (H_ - 1);
  int rest = idx >> 12;
  int ch = rest % C_;
  int b = rest / C_;
  float val = comb[idx];
#pragma unroll
  for (int p = 0; p < 9; ++p) {
    int r0 = (p / 3) * 16, c0 = (p % 3) * 16;
    if (h >= r0 && h < r0 + 32 && w >= c0 && w < c0 + 32)
      val += py[((size_t)(p * B_ + b) * C_ + ch) * NP_ + (h - r0) * 32 + (w - c0)];
  }
  comb[idx] = val;
}

// ---------------- 3x3 conv (SAME) + BN + relu -> out
__global__ __launch_bounds__(256) void k_conv(
    const float* __restrict__ comb, const float* __restrict__ cw,
    const float* __restrict__ cb, const float* __restrict__ cg,
    const float* __restrict__ cbb, const float* __restrict__ cm,
    const float* __restrict__ cv, float* __restrict__ out) {
  int idx = blockIdx.x * 256 + threadIdx.x;
  int w = idx & (W_ - 1);
  int h = (idx >> 6) & (H_ - 1);
  int rest = idx >> 12;
  int o = rest % C_;
  int b = rest / C_;
  float acc = 0.f;
  for (int c = 0; c < C_; ++c) {
    const float* src = comb + ((size_t)(b * C_ + c) * H_) * W_;
    const float* wr = cw + ((size_t)(o * C_ + c)) * 9;
#pragma unroll
    for (int kh = 0; kh < 3; ++kh) {
      int hh = h + kh - 1;
      if (hh < 0 || hh >= H_) continue;
#pragma unroll
      for (int kw = 0; kw < 3; ++kw) {
        int ww = w + kw - 1;
        if (ww < 0 || ww >= W_) continue;
        acc = fmaf(src[hh * W_ + ww], wr[kh * 3 + kw], acc);
      }
    }
  }
  float scale = cg[o] * rsqrtf(cv[o] + EPS_);
  float y = (acc + cb[o] - cm[o]) * scale + cbb[o];
  out[idx] = fmaxf(y, 0.f);
}

extern "C" void kernel_launch(void* const* d_in, const int* in_sizes, int n_in,
                              void* d_out, int out_size, void* d_ws, size_t ws_size,
                              hipStream_t stream) {
  (void)in_sizes; (void)n_in; (void)out_size; (void)ws_size;
  const float* x[4];
  const float* Wall[4];
  const float* Wp[4];
  for (int i = 0; i < 4; ++i) {
    x[i] = (const float*)d_in[i];
    Wall[i] = (const float*)d_in[4 + i];
    Wp[i] = (const float*)d_in[8 + i];
  }
  const float* fuse_w = (const float*)d_in[12];
  const float* fuse_b = (const float*)d_in[13];
  const float* fuse_g = (const float*)d_in[14];
  const float* fuse_bb = (const float*)d_in[15];
  const float* fuse_m = (const float*)d_in[16];
  const float* fuse_v = (const float*)d_in[17];
  const float* fuseP_w = (const float*)d_in[18];
  const float* fuseP_b = (const float*)d_in[19];
  const float* fuseP_g = (const float*)d_in[20];
  const float* fuseP_bb = (const float*)d_in[21];
  const float* fuseP_m = (const float*)d_in[22];
  const float* fuseP_v = (const float*)d_in[23];
  const float* gamma_all = (const float*)d_in[24];
  const float* gamma_p = (const float*)d_in[25];
  const float* out_w = (const float*)d_in[26];
  const float* out_b = (const float*)d_in[27];
  const float* out_g = (const float*)d_in[28];
  const float* out_bb = (const float*)d_in[29];
  const float* out_m = (const float*)d_in[30];
  const float* out_v = (const float*)d_in[31];

  char* base = (char*)d_ws;
  size_t off = 0;
  auto carve = [&](size_t bytes) {
    char* p = base + off;
    off += (bytes + 255) & ~(size_t)255;
    return p;
  };
  f16* projg_n = (f16*)carve((size_t)8 * 48 * N_ * 2);
  f16* projg_t = (f16*)carve((size_t)8 * N_ * 64 * 2);
  f16* projp_n = (f16*)carve((size_t)72 * 48 * NP_ * 2);
  f16* projp_t = (f16*)carve((size_t)72 * NP_ * 64 * 2);
  float* statsg = (float*)carve((size_t)8 * N_ * 4);
  float* statsp = (float*)carve((size_t)72 * NP_ * 4);
  float* cat = (float*)carve((size_t)B_ * C4_ * N_ * 4);
  float* pcat = (float*)carve((size_t)9 * B_ * C4_ * NP_ * 4);
  float* comb = (float*)carve((size_t)B_ * C_ * N_ * 4);
  float* py = (float*)carve((size_t)9 * B_ * C_ * NP_ * 4);

  dim3 blk(256);

  k_proj_g<<<dim3(16, 2, 4), blk, 0, stream>>>(
      x[0], x[1], x[2], x[3], Wall[0], Wall[1], Wall[2], Wall[3], projg_n, projg_t);
  k_proj_p<<<dim3(4, 9, 8), blk, 0, stream>>>(
      x[0], x[1], x[2], x[3], Wp[0], Wp[1], Wp[2], Wp[3], projp_n, projp_t);

  k_stats_f<false><<<dim3(64, 8), blk, 0, stream>>>(projg_t, projg_t, statsg);
  k_stats_f<true><<<dim3(16, 72), blk, 0, stream>>>(projp_t, projp_t, statsp);

  k_pv_f<false><<<dim3(64, 8), blk, 0, stream>>>(projg_t, projg_t, projg_n, statsg, cat);
  k_pv_f<true><<<dim3(16, 72), blk, 0, stream>>>(projp_t, projp_t, projp_n, statsp, pcat);

  k_fuse_global<<<(B_ * C_ * N_) / 256, blk, 0, stream>>>(
      cat, fuse_w, fuse_b, fuse_g, fuse_bb, fuse_m, fuse_v, gamma_all, x[0], comb);
  k_fuse_patch<<<(9 * B_ * C_ * NP_) / 256, blk, 0, stream>>>(
      pcat, fuseP_w, fuseP_b, fuseP_g, fuseP_bb, fuseP_m, fuseP_v, gamma_p, py);
  k_combine<<<(B_ * C_ * N_) / 256, blk, 0, stream>>>(py, comb);
  k_conv<<<(B_ * C_ * N_) / 256, blk, 0, stream>>>(
      comb, out_w, out_b, out_g, out_bb, out_m, out_v, (float*)d_out);
}